// Round 8
// baseline (18.547 us; speedup 1.0000x reference)
//
#include <hip/hip_runtime.h>

#define EDIM 10
#define CDIM 128
#define DDIM 9
#define BDIM 512
#define NT3 165   // #(a<=b<=c) triples over 9 dims
#define NT2 45    // #(a<=b) pairs
#define NT1 9
#define NT 219
#define NUNIT (EDIM * NT)      // 2190 (e,t) table units
#define UPB 4                  // units per block (512 threads = 4 x 128ch)
#define NABLK ((NUNIT + UPB - 1) / UPB)  // 548 table blocks; block 548 = bucket
#define NCH 26    // worst case sum_e ceil(n_e/32) = 512/32 + 10 = 26

// ws layout:
//   T:        [EDIM][NT][CDIM][4] float  (~4.49 MB)  (t-major, c inner: coalesced)
//   sortedB:  int[BDIM]
//   chunkE/S/C: int[NCH] each
#define TABLE_FLOATS ((size_t)EDIM * NT * CDIM * 4)

// ---------------------------------------------------------------------------
// Kernel A: blocks 0..NABLK-1 build the coefficient table, 4 (e,t) units per
// 512-thread block (unit = tid>>7: 2 whole waves each -> u loads wave-uniform,
// w loads + T stores coalesced). Block NABLK buckets rows by species and
// emits same-species chunks of <=32 rows — fully parallel, no serial tail.
// ---------------------------------------------------------------------------
__global__ __launch_bounds__(512) void table_bucket_kernel(
    const float* __restrict__ u1_0e, const float* __restrict__ w1_0e,
    const float* __restrict__ u2_0e, const float* __restrict__ w2_0e,
    const float* __restrict__ u3_0e, const float* __restrict__ w3_0e,
    const float* __restrict__ u1_1o, const float* __restrict__ w1_1o,
    const float* __restrict__ u2_1o, const float* __restrict__ w2_1o,
    const float* __restrict__ u3_1o, const float* __restrict__ w3_1o,
    const float* __restrict__ y,
    float* __restrict__ T, int* __restrict__ sortedB,
    int* __restrict__ chunkE, int* __restrict__ chunkS, int* __restrict__ chunkC) {
  if (blockIdx.x == NABLK) {
    // ---- species bucketing: 512 threads, one row each ----
    __shared__ int cnt[EDIM];
    __shared__ int st[EDIM];
    __shared__ int rk[EDIM];
    const int tid = threadIdx.x;
    if (tid < EDIM) { cnt[tid] = 0; rk[tid] = 0; }
    if (tid >= 64 && tid < 64 + NCH) chunkC[tid - 64] = 0;  // pre-zero chunks
    __syncthreads();
    int e = 0;
    for (int q = 0; q < EDIM; ++q)
      if (y[tid * EDIM + q] > 0.5f) e = q;
    atomicAdd(&cnt[e], 1);
    __syncthreads();
    if (tid < EDIM) {
      int s = 0;
      for (int j = 0; j < tid; ++j) s += cnt[j];
      st[tid] = s;
    }
    __syncthreads();
    if (tid < EDIM) {
      // chunk metadata for my species (order-independent, parallel)
      int base = 0;
      for (int j = 0; j < tid; ++j) base += (cnt[j] + 31) >> 5;
      const int n = cnt[tid];
      const int nch = (n + 31) >> 5;
      for (int k = 0; k < nch; ++k) {
        chunkE[base + k] = tid;
        chunkS[base + k] = st[tid] + 32 * k;
        chunkC[base + k] = (n - 32 * k < 32) ? (n - 32 * k) : 32;
      }
    }
    const int r = atomicAdd(&rk[e], 1);
    sortedB[st[e] + r] = tid;   // order within species irrelevant
    return;
  }

  // ---- table build: unit = blockIdx*UPB + (tid>>7), channel = tid&127 ----
  const int c = threadIdx.x & (CDIM - 1);
  const int unit = blockIdx.x * UPB + (threadIdx.x >> 7);
  if (unit >= NUNIT) return;
  const int e = unit / NT;
  const int t = unit - e * NT;

  float o0 = 0.f, o1 = 0.f, o2 = 0.f, o3 = 0.f;

  if (t < NT3) {
    int r = t, a = 0, b = 0;
    for (a = 0; a < DDIM; ++a) {
      int n = (DDIM - a) * (DDIM - a + 1) / 2;
      if (r < n) break;
      r -= n;
    }
    for (b = a; b < DDIM; ++b) {
      int n = DDIM - b;
      if (r < n) break;
      r -= n;
    }
    const int cc = b + r;
    const float mult = (a == b && b == cc) ? 1.f : ((a == b || b == cc) ? 3.f : 6.f);

    const int ub0 = ((a * DDIM + b) * DDIM + cc) * 8;       // u3_0e: (9,9,9,8,1)
    for (int k = 0; k < 8; ++k)
      o0 += u3_0e[ub0 + k] * w3_0e[(k * EDIM + e) * CDIM + c];

    const int ub1 = ((a * DDIM + b) * DDIM + cc) * 36;      // u3_1o: (9,9,9,12,3)
    for (int k = 0; k < 12; ++k) {
      const float wv = w3_1o[(k * EDIM + e) * CDIM + c];
      o1 += u3_1o[ub1 + k * 3 + 0] * wv;
      o2 += u3_1o[ub1 + k * 3 + 1] * wv;
      o3 += u3_1o[ub1 + k * 3 + 2] * wv;
    }
    o0 *= mult; o1 *= mult; o2 *= mult; o3 *= mult;
  } else if (t < NT3 + NT2) {
    int r = t - NT3, a = 0;
    for (a = 0; a < DDIM; ++a) {
      int n = DDIM - a;
      if (r < n) break;
      r -= n;
    }
    const int b = a + r;
    const float mult = (a == b) ? 1.f : 2.f;

    const int ub0 = (a * DDIM + b) * 3;                     // u2_0e: (9,9,3,1)
    for (int k = 0; k < 3; ++k)
      o0 += u2_0e[ub0 + k] * w2_0e[(k * EDIM + e) * CDIM + c];

    const int ub1 = (a * DDIM + b) * 12;                    // u2_1o: (9,9,4,3)
    for (int k = 0; k < 4; ++k) {
      const float wv = w2_1o[(k * EDIM + e) * CDIM + c];
      o1 += u2_1o[ub1 + k * 3 + 0] * wv;
      o2 += u2_1o[ub1 + k * 3 + 1] * wv;
      o3 += u2_1o[ub1 + k * 3 + 2] * wv;
    }
    o0 *= mult; o1 *= mult; o2 *= mult; o3 *= mult;
  } else {
    const int j = t - NT3 - NT2;
    o0 = u1_0e[j] * w1_0e[e * CDIM + c];                    // u1_0e: (9,1,1)
    const float wv = w1_1o[e * CDIM + c];
    o1 = u1_1o[j * 3 + 0] * wv;                             // u1_1o: (9,1,3)
    o2 = u1_1o[j * 3 + 1] * wv;
    o3 = u1_1o[j * 3 + 2] * wv;
  }

  float4* dst = reinterpret_cast<float4*>(T) + (size_t)(e * NT + t) * CDIM + c;
  *dst = make_float4(o0, o1, o2, o3);
}

// ---------------------------------------------------------------------------
// Kernel B (unchanged from round 7): grid = NCH chunks x 16 channel-tiles.
// Block (256 thr) = 32 same-species rows x 8 channels. Stage the 219x8 slice
// (28 KB) into LDS once (coalesced), then 4 waves run the 219-term polynomial
// from LDS (8 unique 16 B addrs / read -> conflict-free, slot-broadcast).
// ---------------------------------------------------------------------------
__global__ __launch_bounds__(256) void symcon_main_kernel(
    const float* __restrict__ x, const float* __restrict__ T,
    const int* __restrict__ sortedB, const int* __restrict__ chunkE,
    const int* __restrict__ chunkS, const int* __restrict__ chunkC,
    float* __restrict__ out) {
  __shared__ float4 slice[NT * 8];   // 28 KB  [t][cl]
  __shared__ float xs[32 * 72];      // 9.2 KB [slot][cl*9+d]

  const int bid = blockIdx.x;
  const int chunk = bid >> 4;        // 0..NCH-1
  const int ct = bid & 15;           // channel tile (8 ch)
  const int cntc = chunkC[chunk];
  if (cntc == 0) return;
  const int e = chunkE[chunk];
  const int start = chunkS[chunk];

  const int tid = threadIdx.x;
  const int cl = tid & 7;
  const int slot = tid >> 3;         // 0..31
  const int c = ct * 8 + cl;
  const bool valid = (slot < cntc);
  const int b = sortedB[start + (valid ? slot : cntc - 1)];

  // ---- stage coefficient slice: 1752 float4, coalesced 128B groups ----
  {
    const float4* Tg = reinterpret_cast<const float4*>(T) +
                       (size_t)e * NT * CDIM + ct * 8;
#pragma unroll
    for (int k = 0; k < 7; ++k) {
      const int idx = tid + (k << 8);
      if (idx < NT * 8) {
        const int t = idx >> 3;
        const int j = idx & 7;
        slice[idx] = Tg[(size_t)t * CDIM + j];
      }
    }
  }

  // ---- stage x: slot's 8-channel strip, 18 aligned float4 ----
  {
    const float4* gb = reinterpret_cast<const float4*>(
        x + ((size_t)b * CDIM + ct * 8) * DDIM);  // byte off b*4608+ct*288 (16B aligned)
    float4* xf4 = reinterpret_cast<float4*>(&xs[0]);
    xf4[slot * 18 + cl] = gb[cl];
    xf4[slot * 18 + cl + 8] = gb[cl + 8];
    if (cl < 2) xf4[slot * 18 + cl + 16] = gb[cl + 16];
  }
  __syncthreads();

  float xv[DDIM];
#pragma unroll
  for (int d = 0; d < DDIM; ++d)
    xv[d] = xs[slot * 72 + cl * 9 + d];  // 2 lanes/bank -> free

  float a0 = 0.f, a1 = 0.f, a2 = 0.f, a3 = 0.f;
  int t = 0;

  // order 3: a<=b2<=c3 (same enumeration order as the table build)
#pragma unroll
  for (int a = 0; a < DDIM; ++a) {
#pragma unroll
    for (int b2 = a; b2 < DDIM; ++b2) {
      const float xab = xv[a] * xv[b2];
#pragma unroll
      for (int c3 = b2; c3 < DDIM; ++c3) {
        const float m = xab * xv[c3];
        const float4 tv = slice[t * 8 + cl];
        a0 = fmaf(tv.x, m, a0);
        a1 = fmaf(tv.y, m, a1);
        a2 = fmaf(tv.z, m, a2);
        a3 = fmaf(tv.w, m, a3);
        ++t;
      }
    }
  }
  // order 2
#pragma unroll
  for (int a = 0; a < DDIM; ++a) {
#pragma unroll
    for (int b2 = a; b2 < DDIM; ++b2) {
      const float m = xv[a] * xv[b2];
      const float4 tv = slice[t * 8 + cl];
      a0 = fmaf(tv.x, m, a0);
      a1 = fmaf(tv.y, m, a1);
      a2 = fmaf(tv.z, m, a2);
      a3 = fmaf(tv.w, m, a3);
      ++t;
    }
  }
  // order 1
#pragma unroll
  for (int j = 0; j < DDIM; ++j) {
    const float m = xv[j];
    const float4 tv = slice[t * 8 + cl];
    a0 = fmaf(tv.x, m, a0);
    a1 = fmaf(tv.y, m, a1);
    a2 = fmaf(tv.z, m, a2);
    a3 = fmaf(tv.w, m, a3);
    ++t;
  }

  if (valid) {
    float4* o = reinterpret_cast<float4*>(out) + ((size_t)b * CDIM + c);
    *o = make_float4(a0, a1, a2, a3);
  }
}

extern "C" void kernel_launch(void* const* d_in, const int* in_sizes, int n_in,
                              void* d_out, int out_size, void* d_ws, size_t ws_size,
                              hipStream_t stream) {
  const float* x     = (const float*)d_in[0];
  const float* y     = (const float*)d_in[1];
  const float* u1_0e = (const float*)d_in[2];
  const float* w1_0e = (const float*)d_in[3];
  const float* u2_0e = (const float*)d_in[4];
  const float* w2_0e = (const float*)d_in[5];
  const float* u3_0e = (const float*)d_in[6];
  const float* w3_0e = (const float*)d_in[7];
  const float* u1_1o = (const float*)d_in[8];
  const float* w1_1o = (const float*)d_in[9];
  const float* u2_1o = (const float*)d_in[10];
  const float* w2_1o = (const float*)d_in[11];
  const float* u3_1o = (const float*)d_in[12];
  const float* w3_1o = (const float*)d_in[13];

  float* T = (float*)d_ws;
  int* sortedB = (int*)((float*)d_ws + TABLE_FLOATS);
  int* chunkE = sortedB + BDIM;
  int* chunkS = chunkE + NCH;
  int* chunkC = chunkS + NCH;
  float* out = (float*)d_out;

  const size_t need = TABLE_FLOATS * sizeof(float) +
                      (BDIM + 3 * NCH) * sizeof(int);
  if (ws_size < need) return;

  hipLaunchKernelGGL(table_bucket_kernel, dim3(NABLK + 1), dim3(512), 0, stream,
                     u1_0e, w1_0e, u2_0e, w2_0e, u3_0e, w3_0e,
                     u1_1o, w1_1o, u2_1o, w2_1o, u3_1o, w3_1o,
                     y, T, sortedB, chunkE, chunkS, chunkC);

  hipLaunchKernelGGL(symcon_main_kernel, dim3(NCH * 16), dim3(256), 0, stream,
                     x, T, sortedB, chunkE, chunkS, chunkC, out);
}